// Round 1
// baseline (2371.860 us; speedup 1.0000x reference)
//
#include <hip/hip_runtime.h>

#define Bc 4
#define Nc 10000
#define Ec 160000
#define Mc 4
#define Hc 64
#define OUTc 64
#define Fc 64
#define ROWS (Bc * Nc * Mc)   // 160000 rows of [2H=128] -> [OUT=64]
#define TILES (ROWS / 16)     // 10000 MFMA row-tiles

typedef __attribute__((ext_vector_type(8))) short bf16x8;
typedef __attribute__((ext_vector_type(4))) float f32x4;

__device__ __forceinline__ short f2bf(float f) {
    union { float f; unsigned u; } x; x.f = f;
    unsigned r = (x.u + 0x7FFFu + ((x.u >> 16) & 1u)) >> 16;  // RNE truncate to bf16
    return (short)r;
}

// ---------------------------------------------------------------------------
// Kernel 1: nh_fts[r][o] = concat(node,hidden)[r][:] @ W_nh + b_nh
// One wave per 16-row tile. A layout (16x16x32 bf16): A[m=lane&15][k=quad*8+j]
// B layout: B[k=quad*8+j][n=lane&15]. C/D: col=lane&15, row=quad*4+reg.
// ---------------------------------------------------------------------------
__global__ __launch_bounds__(256) void proj_kernel(
    const float* __restrict__ node, const float* __restrict__ hid,
    const float* __restrict__ Wnh, const float* __restrict__ bnh,
    float* __restrict__ nhf)
{
    const int lane  = threadIdx.x & 63;
    const int gwave = (int)((blockIdx.x * blockDim.x + threadIdx.x) >> 6);
    const int nwave = (int)((gridDim.x * blockDim.x) >> 6);
    const int m     = lane & 15;
    const int quad  = lane >> 4;

    // Preload W_nh as bf16 B-fragments: [kt][ct], k = quad*8+32*kt+j, n = m+16*ct
    bf16x8 bfrag[4][4];
#pragma unroll
    for (int kt = 0; kt < 4; ++kt)
#pragma unroll
        for (int ct = 0; ct < 4; ++ct) {
            const int n = m + 16 * ct;
#pragma unroll
            for (int j = 0; j < 8; ++j) {
                const int k = quad * 8 + 32 * kt + j;
                bfrag[kt][ct][j] = f2bf(Wnh[k * 64 + n]);
            }
        }
    float bias[4];
#pragma unroll
    for (int ct = 0; ct < 4; ++ct) bias[ct] = bnh[m + 16 * ct];

    for (int tile = gwave; tile < TILES; tile += nwave) {
        const int arow = tile * 16 + m;   // A-operand row for this lane
        f32x4 acc[4];
#pragma unroll
        for (int ct = 0; ct < 4; ++ct) acc[ct] = (f32x4){0.f, 0.f, 0.f, 0.f};

#pragma unroll
        for (int kt = 0; kt < 4; ++kt) {
            const int kbase = quad * 8 + 32 * kt;  // multiple of 8; never straddles 64
            const float* p = (kbase < 64)
                ? (node + (size_t)arow * 64 + kbase)
                : (hid  + (size_t)arow * 64 + (kbase - 64));
            const float4 lo = *(const float4*)p;
            const float4 hi = *(const float4*)(p + 4);
            bf16x8 a;
            a[0] = f2bf(lo.x); a[1] = f2bf(lo.y); a[2] = f2bf(lo.z); a[3] = f2bf(lo.w);
            a[4] = f2bf(hi.x); a[5] = f2bf(hi.y); a[6] = f2bf(hi.z); a[7] = f2bf(hi.w);
#pragma unroll
            for (int ct = 0; ct < 4; ++ct)
                acc[ct] = __builtin_amdgcn_mfma_f32_16x16x32_bf16(a, bfrag[kt][ct], acc[ct], 0, 0, 0);
        }

        const int r0 = tile * 16 + quad * 4;  // C/D row base for this lane
#pragma unroll
        for (int ct = 0; ct < 4; ++ct) {
            const int col = m + 16 * ct;
#pragma unroll
            for (int reg = 0; reg < 4; ++reg)
                nhf[(size_t)(r0 + reg) * 64 + col] = acc[ct][reg] + bias[ct];
        }
    }
}

// ---------------------------------------------------------------------------
// Kernel 2: per-edge gate + gather + atomic scatter. One wave per edge.
//   coeff = edge_fts[e,:] . W_e + b_e          (shfl_xor reduce over 64 lanes)
//   out[b,tgt,:,:] += coeff * nh_fts[b,src,:,:] (256 floats = 4/lane)
// ---------------------------------------------------------------------------
__global__ __launch_bounds__(256) void edge_kernel(
    const float* __restrict__ efts, const int* __restrict__ eidx,
    const float* __restrict__ We, const float* __restrict__ be,
    const float* __restrict__ nhf, float* __restrict__ out)
{
    const int lane = threadIdx.x & 63;
    const int eg   = (int)((blockIdx.x * blockDim.x + threadIdx.x) >> 6);
    if (eg >= Bc * Ec) return;
    const int b = eg / Ec;

    const float we = We[lane];
    float c = efts[(size_t)eg * 64 + lane] * we;
#pragma unroll
    for (int off = 32; off > 0; off >>= 1) c += __shfl_xor(c, off, 64);
    c += be[0];

    const int src = eidx[(size_t)eg * 2 + 0];
    const int tgt = eidx[(size_t)eg * 2 + 1];

    const float4 v = *(const float4*)(nhf + ((size_t)(b * Nc + src)) * 256 + lane * 4);
    float* op = out + ((size_t)(b * Nc + tgt)) * 256 + lane * 4;
    atomicAdd(op + 0, c * v.x);
    atomicAdd(op + 1, c * v.y);
    atomicAdd(op + 2, c * v.z);
    atomicAdd(op + 3, c * v.w);
}

extern "C" void kernel_launch(void* const* d_in, const int* in_sizes, int n_in,
                              void* d_out, int out_size, void* d_ws, size_t ws_size,
                              hipStream_t stream) {
    const float* node = (const float*)d_in[0];  // [B,N,M,H]
    const float* hid  = (const float*)d_in[1];  // [B,N,M,H]
    const float* efts = (const float*)d_in[2];  // [B,E,F]
    const float* Wnh  = (const float*)d_in[3];  // [2H,OUT]
    const float* bnh  = (const float*)d_in[4];  // [OUT]
    const float* We   = (const float*)d_in[5];  // [F,1]
    const float* be   = (const float*)d_in[6];  // [1]
    const int*   eidx = (const int*)d_in[7];    // [B,E,2] int32
    float* out = (float*)d_out;                 // [B,N,M,OUT]
    float* nhf = (float*)d_ws;                  // scratch: [B,N,M,OUT] = 41 MB

    // zero the scatter target (harness poisons d_out with 0xAA)
    hipMemsetAsync(d_out, 0, (size_t)out_size * sizeof(float), stream);

    // projection: 10000 tiles, grid-stride over 2560 waves
    proj_kernel<<<640, 256, 0, stream>>>(node, hid, Wnh, bnh, nhf);

    // edge scatter: one wave per edge, 4 edges per 256-thread block
    edge_kernel<<<(Bc * Ec) / 4, 256, 0, stream>>>(efts, eidx, We, be, nhf, out);
}

// Round 2
// 592.106 us; speedup vs baseline: 4.0058x; 4.0058x over previous
//
#include <hip/hip_runtime.h>

#define Bc 4
#define Nc 10000
#define Ec 160000
#define Mc 4
#define Hc 64
#define OUTc 64
#define Fc 64
#define ROWS (Bc * Nc * Mc)   // 160000 rows of [2H=128] -> [OUT=64]
#define TILES (ROWS / 16)     // 10000 MFMA row-tiles
#define NSEG (Bc * Nc)        // 40000 scatter segments
#define NEDGE (Bc * Ec)       // 640000 edges

typedef __attribute__((ext_vector_type(8))) short bf16x8;
typedef __attribute__((ext_vector_type(4))) float f32x4;

__device__ __forceinline__ short f2bf(float f) {
    union { float f; unsigned u; } x; x.f = f;
    unsigned r = (x.u + 0x7FFFu + ((x.u >> 16) & 1u)) >> 16;  // RNE truncate to bf16
    return (short)r;
}

// ---------------------------------------------------------------------------
// Kernel 1: nh_fts[r][o] = concat(node,hidden)[r][:] @ W_nh + b_nh
// One wave per 16-row tile. A layout (16x16x32 bf16): A[m=lane&15][k=quad*8+j]
// B layout: B[k=quad*8+j][n=lane&15]. C/D: col=lane&15, row=quad*4+reg.
// ---------------------------------------------------------------------------
__global__ __launch_bounds__(256) void proj_kernel(
    const float* __restrict__ node, const float* __restrict__ hid,
    const float* __restrict__ Wnh, const float* __restrict__ bnh,
    float* __restrict__ nhf)
{
    const int lane  = threadIdx.x & 63;
    const int gwave = (int)((blockIdx.x * blockDim.x + threadIdx.x) >> 6);
    const int nwave = (int)((gridDim.x * blockDim.x) >> 6);
    const int m     = lane & 15;
    const int quad  = lane >> 4;

    // Preload W_nh as bf16 B-fragments: [kt][ct], k = quad*8+32*kt+j, n = m+16*ct
    bf16x8 bfrag[4][4];
#pragma unroll
    for (int kt = 0; kt < 4; ++kt)
#pragma unroll
        for (int ct = 0; ct < 4; ++ct) {
            const int n = m + 16 * ct;
#pragma unroll
            for (int j = 0; j < 8; ++j) {
                const int k = quad * 8 + 32 * kt + j;
                bfrag[kt][ct][j] = f2bf(Wnh[k * 64 + n]);
            }
        }
    float bias[4];
#pragma unroll
    for (int ct = 0; ct < 4; ++ct) bias[ct] = bnh[m + 16 * ct];

    for (int tile = gwave; tile < TILES; tile += nwave) {
        const int arow = tile * 16 + m;   // A-operand row for this lane
        f32x4 acc[4];
#pragma unroll
        for (int ct = 0; ct < 4; ++ct) acc[ct] = (f32x4){0.f, 0.f, 0.f, 0.f};

#pragma unroll
        for (int kt = 0; kt < 4; ++kt) {
            const int kbase = quad * 8 + 32 * kt;  // multiple of 8; never straddles 64
            const float* p = (kbase < 64)
                ? (node + (size_t)arow * 64 + kbase)
                : (hid  + (size_t)arow * 64 + (kbase - 64));
            const float4 lo = *(const float4*)p;
            const float4 hi = *(const float4*)(p + 4);
            bf16x8 a;
            a[0] = f2bf(lo.x); a[1] = f2bf(lo.y); a[2] = f2bf(lo.z); a[3] = f2bf(lo.w);
            a[4] = f2bf(hi.x); a[5] = f2bf(hi.y); a[6] = f2bf(hi.z); a[7] = f2bf(hi.w);
#pragma unroll
            for (int ct = 0; ct < 4; ++ct)
                acc[ct] = __builtin_amdgcn_mfma_f32_16x16x32_bf16(a, bfrag[kt][ct], acc[ct], 0, 0, 0);
        }

        const int r0 = tile * 16 + quad * 4;  // C/D row base for this lane
#pragma unroll
        for (int ct = 0; ct < 4; ++ct) {
            const int col = m + 16 * ct;
#pragma unroll
            for (int reg = 0; reg < 4; ++reg)
                nhf[(size_t)(r0 + reg) * 64 + col] = acc[ct][reg] + bias[ct];
        }
    }
}

// ---------------------------------------------------------------------------
// Kernel 2: per-edge gate coeff + degree histogram. One wave per edge.
// ---------------------------------------------------------------------------
__global__ __launch_bounds__(256) void gate_kernel(
    const float* __restrict__ efts, const int* __restrict__ eidx,
    const float* __restrict__ We, const float* __restrict__ be,
    float* __restrict__ coeff, int* __restrict__ cnt)
{
    const int lane = threadIdx.x & 63;
    const int eg   = (int)((blockIdx.x * blockDim.x + threadIdx.x) >> 6);
    if (eg >= NEDGE) return;
    float c = efts[(size_t)eg * 64 + lane] * We[lane];
#pragma unroll
    for (int off = 32; off > 0; off >>= 1) c += __shfl_xor(c, off, 64);
    if (lane == 0) {
        const int b   = eg / Ec;
        const int tgt = eidx[(size_t)eg * 2 + 1];
        coeff[eg] = c + be[0];
        atomicAdd(&cnt[b * Nc + tgt], 1);
    }
}

// ---------------------------------------------------------------------------
// Kernel 3: exclusive prefix sum over NSEG=40000 degree counts. One block.
// ---------------------------------------------------------------------------
__global__ __launch_bounds__(1024) void scan_kernel(
    const int* __restrict__ cnt, int* __restrict__ offs)
{
    __shared__ int part[1024];
    const int t = threadIdx.x;
    const int CH = (NSEG + 1023) / 1024;  // 40
    const int base = t * CH;
    int s = 0;
    for (int i = 0; i < CH; ++i) {
        const int idx = base + i;
        if (idx < NSEG) s += cnt[idx];
    }
    part[t] = s;
    __syncthreads();
    for (int off = 1; off < 1024; off <<= 1) {
        int v = (t >= off) ? part[t - off] : 0;
        __syncthreads();
        part[t] += v;
        __syncthreads();
    }
    int run = (t == 0) ? 0 : part[t - 1];
    for (int i = 0; i < CH; ++i) {
        const int idx = base + i;
        if (idx < NSEG) { offs[idx] = run; run += cnt[idx]; }
    }
    if (t == 1023) offs[NSEG] = run;  // total = NEDGE
}

// ---------------------------------------------------------------------------
// Kernel 4: scatter (src, coeff) into CSR slots. One thread per edge.
// ---------------------------------------------------------------------------
__global__ __launch_bounds__(256) void fill_kernel(
    const int* __restrict__ eidx, const float* __restrict__ coeff,
    const int* __restrict__ offs, int* __restrict__ cursor,
    int* __restrict__ esrc, float* __restrict__ ecoef)
{
    const int eg = (int)(blockIdx.x * blockDim.x + threadIdx.x);
    if (eg >= NEDGE) return;
    const int b   = eg / Ec;
    const int src = eidx[(size_t)eg * 2 + 0];
    const int tgt = eidx[(size_t)eg * 2 + 1];
    const int seg = b * Nc + tgt;
    const int pos  = atomicAdd(&cursor[seg], 1);
    const int slot = offs[seg] + pos;
    esrc[slot]  = src;
    ecoef[slot] = coeff[eg];
}

// ---------------------------------------------------------------------------
// Kernel 5: per-node register accumulation over CSR edge list. One wave/node.
// out[b,n,:,:] = sum_e coeff[e] * nhf[b,src[e],:,:]   (256 floats = 4/lane)
// ---------------------------------------------------------------------------
__global__ __launch_bounds__(256) void gather_kernel(
    const int* __restrict__ offs, const int* __restrict__ esrc,
    const float* __restrict__ ecoef, const float* __restrict__ nhf,
    float* __restrict__ out)
{
    const int lane = threadIdx.x & 63;
    const int seg  = (int)((blockIdx.x * blockDim.x + threadIdx.x) >> 6);
    if (seg >= NSEG) return;
    const int b = seg / Nc;
    const int start = offs[seg], end = offs[seg + 1];
    const float* base = nhf + (size_t)b * Nc * 256;
    float4 acc = {0.f, 0.f, 0.f, 0.f};
    for (int i = start; i < end; ++i) {
        const int   src = esrc[i];
        const float c   = ecoef[i];
        const float4 v = *(const float4*)(base + (size_t)src * 256 + lane * 4);
        acc.x += c * v.x; acc.y += c * v.y; acc.z += c * v.z; acc.w += c * v.w;
    }
    *(float4*)(out + (size_t)seg * 256 + lane * 4) = acc;
}

// ---------------------------------------------------------------------------
// Fallback (ws too small): per-edge atomic scatter (the R1 path).
// ---------------------------------------------------------------------------
__global__ __launch_bounds__(256) void edge_atomic_kernel(
    const float* __restrict__ efts, const int* __restrict__ eidx,
    const float* __restrict__ We, const float* __restrict__ be,
    const float* __restrict__ nhf, float* __restrict__ out)
{
    const int lane = threadIdx.x & 63;
    const int eg   = (int)((blockIdx.x * blockDim.x + threadIdx.x) >> 6);
    if (eg >= NEDGE) return;
    const int b = eg / Ec;
    float c = efts[(size_t)eg * 64 + lane] * We[lane];
#pragma unroll
    for (int off = 32; off > 0; off >>= 1) c += __shfl_xor(c, off, 64);
    c += be[0];
    const int src = eidx[(size_t)eg * 2 + 0];
    const int tgt = eidx[(size_t)eg * 2 + 1];
    const float4 v = *(const float4*)(nhf + ((size_t)(b * Nc + src)) * 256 + lane * 4);
    float* op = out + ((size_t)(b * Nc + tgt)) * 256 + lane * 4;
    atomicAdd(op + 0, c * v.x);
    atomicAdd(op + 1, c * v.y);
    atomicAdd(op + 2, c * v.z);
    atomicAdd(op + 3, c * v.w);
}

extern "C" void kernel_launch(void* const* d_in, const int* in_sizes, int n_in,
                              void* d_out, int out_size, void* d_ws, size_t ws_size,
                              hipStream_t stream) {
    const float* node = (const float*)d_in[0];  // [B,N,M,H]
    const float* hid  = (const float*)d_in[1];  // [B,N,M,H]
    const float* efts = (const float*)d_in[2];  // [B,E,F]
    const float* Wnh  = (const float*)d_in[3];  // [2H,OUT]
    const float* bnh  = (const float*)d_in[4];  // [OUT]
    const float* We   = (const float*)d_in[5];  // [F,1]
    const float* be   = (const float*)d_in[6];  // [1]
    const int*   eidx = (const int*)d_in[7];    // [B,E,2] int32
    float* out = (float*)d_out;                 // [B,N,M,OUT]

    // Workspace layout (element offsets, 4 B each):
    //   nhf    [0,          10,240,000)   projected features
    //   coeff  [10,240,000, 10,880,000)   per-edge gate
    //   ecoef  [10,880,000, 11,520,000)   CSR-ordered gate
    //   esrc   [11,520,000, 12,160,000)   CSR-ordered src ids
    //   cnt    [12,160,000, 12,200,000)   per-segment degree
    //   cursor [12,200,000, 12,240,000)   fill cursors
    //   offs   [12,240,000, 12,280,001)   CSR offsets
    float* nhf    = (float*)d_ws;
    float* coeff  = nhf + 10240000;
    float* ecoef  = nhf + 10880000;
    int*   esrc   = (int*)(nhf + 11520000);
    int*   cnt    = (int*)(nhf + 12160000);
    int*   cursor = (int*)(nhf + 12200000);
    int*   offs   = (int*)(nhf + 12240000);
    const size_t ws_needed = (size_t)12280001 * 4;

    // projection: 10000 tiles, one per wave
    proj_kernel<<<2500, 256, 0, stream>>>(node, hid, Wnh, bnh, nhf);

    if (ws_size >= ws_needed) {
        // zero cnt + cursor (adjacent: 80,000 ints)
        hipMemsetAsync(cnt, 0, (size_t)80000 * sizeof(int), stream);
        gate_kernel<<<NEDGE / 4, 256, 0, stream>>>(efts, eidx, We, be, coeff, cnt);
        scan_kernel<<<1, 1024, 0, stream>>>(cnt, offs);
        fill_kernel<<<NEDGE / 256, 256, 0, stream>>>(eidx, coeff, offs, cursor, esrc, ecoef);
        gather_kernel<<<NSEG / 4, 256, 0, stream>>>(offs, esrc, ecoef, nhf, out);
    } else {
        hipMemsetAsync(d_out, 0, (size_t)out_size * sizeof(float), stream);
        edge_atomic_kernel<<<NEDGE / 4, 256, 0, stream>>>(efts, eidx, We, be, nhf, out);
    }
}

// Round 3
// 461.610 us; speedup vs baseline: 5.1382x; 1.2827x over previous
//
#include <hip/hip_runtime.h>

#define Bc 4
#define Nc 10000
#define Ec 160000
#define Mc 4
#define Hc 64
#define OUTc 64
#define Fc 64
#define ROWS (Bc * Nc * Mc)   // 160000 rows of [2H=128] -> [OUT=64]
#define TILES (ROWS / 16)     // 10000 MFMA row-tiles
#define NSEG (Bc * Nc)        // 40000 scatter segments
#define NEDGE (Bc * Ec)       // 640000 edges

typedef __attribute__((ext_vector_type(8))) short bf16x8;
typedef __attribute__((ext_vector_type(4))) float f32x4;

__device__ __forceinline__ unsigned short f2bf(float f) {
    union { float f; unsigned u; } x; x.f = f;
    return (unsigned short)((x.u + 0x7FFFu + ((x.u >> 16) & 1u)) >> 16);  // RNE
}
__device__ __forceinline__ float bfhi(unsigned u) {   // high 16 bits as bf16
    union { unsigned u; float f; } x; x.u = u & 0xFFFF0000u; return x.f;
}
__device__ __forceinline__ float bflo(unsigned u) {   // low 16 bits as bf16
    union { unsigned u; float f; } x; x.u = u << 16; return x.f;
}

// ---------------------------------------------------------------------------
// Kernel 1: nh_fts[r][o] = concat(node,hidden)[r][:] @ W_nh + b_nh
// One wave per 16-row tile; output stored as bf16 (halves gather traffic).
// A layout (16x16x32 bf16): A[m=lane&15][k=quad*8+j]; B[k=quad*8+j][n=lane&15].
// C/D: col=lane&15, row=quad*4+reg.
// ---------------------------------------------------------------------------
__global__ __launch_bounds__(256) void proj_kernel(
    const float* __restrict__ node, const float* __restrict__ hid,
    const float* __restrict__ Wnh, const float* __restrict__ bnh,
    unsigned short* __restrict__ nhf)
{
    const int lane  = threadIdx.x & 63;
    const int gwave = (int)((blockIdx.x * blockDim.x + threadIdx.x) >> 6);
    const int nwave = (int)((gridDim.x * blockDim.x) >> 6);
    const int m     = lane & 15;
    const int quad  = lane >> 4;

    bf16x8 bfrag[4][4];
#pragma unroll
    for (int kt = 0; kt < 4; ++kt)
#pragma unroll
        for (int ct = 0; ct < 4; ++ct) {
            const int n = m + 16 * ct;
#pragma unroll
            for (int j = 0; j < 8; ++j) {
                const int k = quad * 8 + 32 * kt + j;
                bfrag[kt][ct][j] = (short)f2bf(Wnh[k * 64 + n]);
            }
        }
    float bias[4];
#pragma unroll
    for (int ct = 0; ct < 4; ++ct) bias[ct] = bnh[m + 16 * ct];

    for (int tile = gwave; tile < TILES; tile += nwave) {
        const int arow = tile * 16 + m;
        f32x4 acc[4];
#pragma unroll
        for (int ct = 0; ct < 4; ++ct) acc[ct] = (f32x4){0.f, 0.f, 0.f, 0.f};

#pragma unroll
        for (int kt = 0; kt < 4; ++kt) {
            const int kbase = quad * 8 + 32 * kt;  // multiple of 8; never straddles 64
            const float* p = (kbase < 64)
                ? (node + (size_t)arow * 64 + kbase)
                : (hid  + (size_t)arow * 64 + (kbase - 64));
            const float4 lo = *(const float4*)p;
            const float4 hi = *(const float4*)(p + 4);
            bf16x8 a;
            a[0] = (short)f2bf(lo.x); a[1] = (short)f2bf(lo.y);
            a[2] = (short)f2bf(lo.z); a[3] = (short)f2bf(lo.w);
            a[4] = (short)f2bf(hi.x); a[5] = (short)f2bf(hi.y);
            a[6] = (short)f2bf(hi.z); a[7] = (short)f2bf(hi.w);
#pragma unroll
            for (int ct = 0; ct < 4; ++ct)
                acc[ct] = __builtin_amdgcn_mfma_f32_16x16x32_bf16(a, bfrag[kt][ct], acc[ct], 0, 0, 0);
        }

        const int r0 = tile * 16 + quad * 4;
#pragma unroll
        for (int ct = 0; ct < 4; ++ct) {
            const int col = m + 16 * ct;
#pragma unroll
            for (int reg = 0; reg < 4; ++reg)
                nhf[(size_t)(r0 + reg) * 64 + col] = f2bf(acc[ct][reg] + bias[ct]);
        }
    }
}

// ---------------------------------------------------------------------------
// Kernel 2: gate coeff + degree histogram. 16 edges per wave.
// float4 index f = j*64+lane covers edge e0 + 4j + (lane>>4), chunk lane&15.
// 4 KB in flight per wave (vs 256 B in the R2 version — latency fix).
// ---------------------------------------------------------------------------
__global__ __launch_bounds__(256) void gate_kernel(
    const float* __restrict__ efts, const int* __restrict__ eidx,
    const float* __restrict__ We, const float* __restrict__ be,
    float* __restrict__ coeff, int* __restrict__ cnt)
{
    const int lane = threadIdx.x & 63;
    const int w    = (int)((blockIdx.x * blockDim.x + threadIdx.x) >> 6);
    const int e0   = w * 16;
    if (e0 >= NEDGE) return;

    const float4 w4 = *(const float4*)(We + (lane & 15) * 4);
    const float* base = efts + (size_t)e0 * 64;
    float p[4];
#pragma unroll
    for (int j = 0; j < 4; ++j) {
        const float4 v = *(const float4*)(base + (size_t)(j * 64 + lane) * 4);
        p[j] = v.x * w4.x + v.y * w4.y + v.z * w4.z + v.w * w4.w;
    }
#pragma unroll
    for (int off = 1; off < 16; off <<= 1) {
#pragma unroll
        for (int j = 0; j < 4; ++j) p[j] += __shfl_xor(p[j], off, 64);
    }
    if ((lane & 15) == 0) {
        const int g = lane >> 4;
        const float bb = be[0];
#pragma unroll
        for (int j = 0; j < 4; ++j) {
            const int e = e0 + 4 * j + g;
            coeff[e] = p[j] + bb;
            const int b   = e / Ec;
            const int tgt = eidx[(size_t)e * 2 + 1];
            atomicAdd(&cnt[b * Nc + tgt], 1);
        }
    }
}

// ---------------------------------------------------------------------------
// Kernel 3: exclusive prefix sum over NSEG=40000 degree counts. One block.
// ---------------------------------------------------------------------------
__global__ __launch_bounds__(1024) void scan_kernel(
    const int* __restrict__ cnt, int* __restrict__ offs)
{
    __shared__ int part[1024];
    const int t = threadIdx.x;
    const int CH = (NSEG + 1023) / 1024;  // 40
    const int base = t * CH;
    int s = 0;
    for (int i = 0; i < CH; ++i) {
        const int idx = base + i;
        if (idx < NSEG) s += cnt[idx];
    }
    part[t] = s;
    __syncthreads();
    for (int off = 1; off < 1024; off <<= 1) {
        int v = (t >= off) ? part[t - off] : 0;
        __syncthreads();
        part[t] += v;
        __syncthreads();
    }
    int run = (t == 0) ? 0 : part[t - 1];
    for (int i = 0; i < CH; ++i) {
        const int idx = base + i;
        if (idx < NSEG) { offs[idx] = run; run += cnt[idx]; }
    }
    if (t == 1023) offs[NSEG] = run;  // total = NEDGE
}

// ---------------------------------------------------------------------------
// Kernel 4: scatter packed (src, coeff) into CSR slots. One thread per edge.
// ---------------------------------------------------------------------------
__global__ __launch_bounds__(256) void fill_kernel(
    const int* __restrict__ eidx, const float* __restrict__ coeff,
    const int* __restrict__ offs, int* __restrict__ cursor,
    int2* __restrict__ epair)
{
    const int eg = (int)(blockIdx.x * blockDim.x + threadIdx.x);
    if (eg >= NEDGE) return;
    const int b   = eg / Ec;
    const int src = eidx[(size_t)eg * 2 + 0];
    const int tgt = eidx[(size_t)eg * 2 + 1];
    const int seg = b * Nc + tgt;
    const int slot = offs[seg] + atomicAdd(&cursor[seg], 1);
    epair[slot] = make_int2(src, __float_as_int(coeff[eg]));
}

// ---------------------------------------------------------------------------
// Kernel 5: per-node register accumulation over CSR edge list. One wave/node.
// nhf rows are bf16 (128 uints per node-block of 256 elems). Unroll x4 with
// independent accumulators; (src,coeff) pairs are wave-uniform scalar loads.
// ---------------------------------------------------------------------------
__global__ __launch_bounds__(256) void gather_kernel(
    const int* __restrict__ offs, const int2* __restrict__ epair,
    const unsigned* __restrict__ nhf, float* __restrict__ out)
{
    const int lane = threadIdx.x & 63;
    int seg = (int)((blockIdx.x * blockDim.x + threadIdx.x) >> 6);
    if (seg >= NSEG) return;
    seg = __builtin_amdgcn_readfirstlane(seg);
    const int b = seg / Nc;
    const int start = offs[seg], end = offs[seg + 1];
    const unsigned* base = nhf + (size_t)b * Nc * 128 + lane * 2;

    float4 a0 = {0.f,0.f,0.f,0.f}, a1 = {0.f,0.f,0.f,0.f};
    float4 a2 = {0.f,0.f,0.f,0.f}, a3 = {0.f,0.f,0.f,0.f};
    int i = start;
    for (; i + 4 <= end; i += 4) {
        const int2 p0 = epair[i + 0], p1 = epair[i + 1];
        const int2 p2 = epair[i + 2], p3 = epair[i + 3];
        const uint2 r0 = *(const uint2*)(base + (size_t)p0.x * 128);
        const uint2 r1 = *(const uint2*)(base + (size_t)p1.x * 128);
        const uint2 r2 = *(const uint2*)(base + (size_t)p2.x * 128);
        const uint2 r3 = *(const uint2*)(base + (size_t)p3.x * 128);
        const float c0 = __int_as_float(p0.y), c1 = __int_as_float(p1.y);
        const float c2 = __int_as_float(p2.y), c3 = __int_as_float(p3.y);
        a0.x += c0 * bflo(r0.x); a0.y += c0 * bfhi(r0.x);
        a0.z += c0 * bflo(r0.y); a0.w += c0 * bfhi(r0.y);
        a1.x += c1 * bflo(r1.x); a1.y += c1 * bfhi(r1.x);
        a1.z += c1 * bflo(r1.y); a1.w += c1 * bfhi(r1.y);
        a2.x += c2 * bflo(r2.x); a2.y += c2 * bfhi(r2.x);
        a2.z += c2 * bflo(r2.y); a2.w += c2 * bfhi(r2.y);
        a3.x += c3 * bflo(r3.x); a3.y += c3 * bfhi(r3.x);
        a3.z += c3 * bflo(r3.y); a3.w += c3 * bfhi(r3.y);
    }
    for (; i < end; ++i) {
        const int2 p = epair[i];
        const uint2 r = *(const uint2*)(base + (size_t)p.x * 128);
        const float c = __int_as_float(p.y);
        a0.x += c * bflo(r.x); a0.y += c * bfhi(r.x);
        a0.z += c * bflo(r.y); a0.w += c * bfhi(r.y);
    }
    float4 acc;
    acc.x = (a0.x + a1.x) + (a2.x + a3.x);
    acc.y = (a0.y + a1.y) + (a2.y + a3.y);
    acc.z = (a0.z + a1.z) + (a2.z + a3.z);
    acc.w = (a0.w + a1.w) + (a2.w + a3.w);
    *(float4*)(out + (size_t)seg * 256 + lane * 4) = acc;
}

// ---------------------------------------------------------------------------
// Fallback (ws too small): per-edge atomic scatter over bf16 nhf.
// ---------------------------------------------------------------------------
__global__ __launch_bounds__(256) void edge_atomic_kernel(
    const float* __restrict__ efts, const int* __restrict__ eidx,
    const float* __restrict__ We, const float* __restrict__ be,
    const unsigned* __restrict__ nhf, float* __restrict__ out)
{
    const int lane = threadIdx.x & 63;
    const int eg   = (int)((blockIdx.x * blockDim.x + threadIdx.x) >> 6);
    if (eg >= NEDGE) return;
    const int b = eg / Ec;
    float c = efts[(size_t)eg * 64 + lane] * We[lane];
#pragma unroll
    for (int off = 32; off > 0; off >>= 1) c += __shfl_xor(c, off, 64);
    c += be[0];
    const int src = eidx[(size_t)eg * 2 + 0];
    const int tgt = eidx[(size_t)eg * 2 + 1];
    const uint2 r = *(const uint2*)(nhf + ((size_t)(b * Nc + src)) * 128 + lane * 2);
    float* op = out + ((size_t)(b * Nc + tgt)) * 256 + lane * 4;
    atomicAdd(op + 0, c * bflo(r.x));
    atomicAdd(op + 1, c * bfhi(r.x));
    atomicAdd(op + 2, c * bflo(r.y));
    atomicAdd(op + 3, c * bfhi(r.y));
}

extern "C" void kernel_launch(void* const* d_in, const int* in_sizes, int n_in,
                              void* d_out, int out_size, void* d_ws, size_t ws_size,
                              hipStream_t stream) {
    const float* node = (const float*)d_in[0];  // [B,N,M,H]
    const float* hid  = (const float*)d_in[1];  // [B,N,M,H]
    const float* efts = (const float*)d_in[2];  // [B,E,F]
    const float* Wnh  = (const float*)d_in[3];  // [2H,OUT]
    const float* bnh  = (const float*)d_in[4];  // [OUT]
    const float* We   = (const float*)d_in[5];  // [F,1]
    const float* be   = (const float*)d_in[6];  // [1]
    const int*   eidx = (const int*)d_in[7];    // [B,E,2] int32
    float* out = (float*)d_out;                 // [B,N,M,OUT]

    // Workspace layout (4-byte element offsets):
    //   nhf16  [0,         5,120,000)  bf16 projected features (10.24M ushort)
    //   coeff  [5,120,000, 5,760,000)  per-edge gate (float)
    //   epair  [5,760,000, 7,040,000)  CSR (src, coeff) int2 pairs
    //   cnt    [7,040,000, 7,080,000)
    //   cursor [7,080,000, 7,120,000)
    //   offs   [7,120,000, 7,160,001)
    unsigned* ws   = (unsigned*)d_ws;
    unsigned short* nhf16 = (unsigned short*)ws;
    float* coeff   = (float*)(ws + 5120000);
    int2*  epair   = (int2*)(ws + 5760000);
    int*   cnt     = (int*)(ws + 7040000);
    int*   cursor  = (int*)(ws + 7080000);
    int*   offs    = (int*)(ws + 7120000);
    const size_t ws_needed = (size_t)7160001 * 4;

    proj_kernel<<<2500, 256, 0, stream>>>(node, hid, Wnh, bnh, nhf16);

    if (ws_size >= ws_needed) {
        hipMemsetAsync(cnt, 0, (size_t)80000 * sizeof(int), stream);  // cnt+cursor
        gate_kernel<<<NEDGE / 64, 256, 0, stream>>>(efts, eidx, We, be, coeff, cnt);
        scan_kernel<<<1, 1024, 0, stream>>>(cnt, offs);
        fill_kernel<<<NEDGE / 256, 256, 0, stream>>>(eidx, coeff, offs, cursor, epair);
        gather_kernel<<<NSEG / 4, 256, 0, stream>>>(offs, epair, (const unsigned*)ws, out);
    } else {
        hipMemsetAsync(d_out, 0, (size_t)out_size * sizeof(float), stream);
        edge_atomic_kernel<<<NEDGE / 4, 256, 0, stream>>>(efts, eidx, We, be, (const unsigned*)ws, out);
    }
}

// Round 4
// 453.734 us; speedup vs baseline: 5.2274x; 1.0174x over previous
//
#include <hip/hip_runtime.h>

#define Bc 4
#define Nc 10000
#define Ec 160000
#define Mc 4
#define Hc 64
#define OUTc 64
#define Fc 64
#define ROWS (Bc * Nc * Mc)   // 160000 rows of [2H=128] -> [OUT=64]
#define TILES (ROWS / 16)     // 10000 MFMA row-tiles
#define NSEG (Bc * Nc)        // 40000 scatter segments
#define NEDGE (Bc * Ec)       // 640000 edges
#define PROJ_BLOCKS 2500      // 4 waves/block * 2500 = 10000 tiles
#define GATE_BLOCKS 10000     // 4 waves/block * 16 edges/wave * 10000 = 640000

typedef __attribute__((ext_vector_type(8))) short bf16x8;
typedef __attribute__((ext_vector_type(4))) float f32x4;

__device__ __forceinline__ unsigned short f2bf(float f) {
    union { float f; unsigned u; } x; x.f = f;
    return (unsigned short)((x.u + 0x7FFFu + ((x.u >> 16) & 1u)) >> 16);  // RNE
}
__device__ __forceinline__ float bfhi(unsigned u) {
    union { unsigned u; float f; } x; x.u = u & 0xFFFF0000u; return x.f;
}
__device__ __forceinline__ float bflo(unsigned u) {
    union { unsigned u; float f; } x; x.u = u << 16; return x.f;
}

// ---------------------------------------------------------------------------
// Fused kernel 1: blocks [0, PROJ_BLOCKS) project nh_fts (MFMA, bf16 out);
// blocks [PROJ_BLOCKS, PROJ_BLOCKS+GATE_BLOCKS) compute edge gates + degree
// histogram. Disjoint inputs/outputs; fusion overlaps the two HBM streams
// (82 MB node/hid + 164 MB edge_fts) in one dispatch.
// ---------------------------------------------------------------------------
__global__ __launch_bounds__(256) void proj_gate_kernel(
    const float* __restrict__ node, const float* __restrict__ hid,
    const float* __restrict__ Wnh, const float* __restrict__ bnh,
    unsigned short* __restrict__ nhf,
    const float* __restrict__ efts, const int* __restrict__ eidx,
    const float* __restrict__ We, const float* __restrict__ be,
    float* __restrict__ coeff, int* __restrict__ cnt)
{
    const int lane = threadIdx.x & 63;

    if (blockIdx.x < PROJ_BLOCKS) {
        // ----- projection: one 16-row MFMA tile per wave -----
        // A layout (16x16x32 bf16): A[m=lane&15][k=quad*8+j];
        // B[k=quad*8+j][n=lane&15]. C/D: col=lane&15, row=quad*4+reg.
        const int tile = (int)(blockIdx.x * 4 + (threadIdx.x >> 6));
        const int m    = lane & 15;
        const int quad = lane >> 4;

        bf16x8 bfrag[4][4];
#pragma unroll
        for (int kt = 0; kt < 4; ++kt)
#pragma unroll
            for (int ct = 0; ct < 4; ++ct) {
                const int n = m + 16 * ct;
#pragma unroll
                for (int j = 0; j < 8; ++j) {
                    const int k = quad * 8 + 32 * kt + j;
                    bfrag[kt][ct][j] = (short)f2bf(Wnh[k * 64 + n]);
                }
            }
        float bias[4];
#pragma unroll
        for (int ct = 0; ct < 4; ++ct) bias[ct] = bnh[m + 16 * ct];

        const int arow = tile * 16 + m;
        f32x4 acc[4];
#pragma unroll
        for (int ct = 0; ct < 4; ++ct) acc[ct] = (f32x4){0.f, 0.f, 0.f, 0.f};

#pragma unroll
        for (int kt = 0; kt < 4; ++kt) {
            const int kbase = quad * 8 + 32 * kt;  // multiple of 8; never straddles 64
            const float* p = (kbase < 64)
                ? (node + (size_t)arow * 64 + kbase)
                : (hid  + (size_t)arow * 64 + (kbase - 64));
            const float4 lo = *(const float4*)p;
            const float4 hi = *(const float4*)(p + 4);
            bf16x8 a;
            a[0] = (short)f2bf(lo.x); a[1] = (short)f2bf(lo.y);
            a[2] = (short)f2bf(lo.z); a[3] = (short)f2bf(lo.w);
            a[4] = (short)f2bf(hi.x); a[5] = (short)f2bf(hi.y);
            a[6] = (short)f2bf(hi.z); a[7] = (short)f2bf(hi.w);
#pragma unroll
            for (int ct = 0; ct < 4; ++ct)
                acc[ct] = __builtin_amdgcn_mfma_f32_16x16x32_bf16(a, bfrag[kt][ct], acc[ct], 0, 0, 0);
        }

        const int r0 = tile * 16 + quad * 4;
#pragma unroll
        for (int ct = 0; ct < 4; ++ct) {
            const int col = m + 16 * ct;
#pragma unroll
            for (int reg = 0; reg < 4; ++reg)
                nhf[(size_t)(r0 + reg) * 64 + col] = f2bf(acc[ct][reg] + bias[ct]);
        }
    } else {
        // ----- gate: 16 edges per wave; 4 KB in flight -----
        const int w  = (int)((blockIdx.x - PROJ_BLOCKS) * 4 + (threadIdx.x >> 6));
        const int e0 = w * 16;                 // Ec % 16 == 0: whole wave in one batch
        if (e0 >= NEDGE) return;
        const int b  = e0 / Ec;

        const float4 w4 = *(const float4*)(We + (lane & 15) * 4);
        const float* base = efts + (size_t)e0 * 64;
        float p[4];
#pragma unroll
        for (int j = 0; j < 4; ++j) {
            const float4 v = *(const float4*)(base + (size_t)(j * 64 + lane) * 4);
            p[j] = v.x * w4.x + v.y * w4.y + v.z * w4.z + v.w * w4.w;
        }
#pragma unroll
        for (int off = 1; off < 16; off <<= 1) {
#pragma unroll
            for (int j = 0; j < 4; ++j) p[j] += __shfl_xor(p[j], off, 64);
        }
        if ((lane & 15) == 0) {
            const int g = lane >> 4;
            const float bb = be[0];
            const int cb = b * Nc;
#pragma unroll
            for (int j = 0; j < 4; ++j) {
                const int e = e0 + 4 * j + g;
                coeff[e] = p[j] + bb;
                const int tgt = eidx[(size_t)e * 2 + 1];
                atomicAdd(&cnt[cb + tgt], 1);
            }
        }
    }
}

// ---------------------------------------------------------------------------
// Kernel 2: exclusive prefix sum over NSEG=40000 degree counts. One block.
// ---------------------------------------------------------------------------
__global__ __launch_bounds__(1024) void scan_kernel(
    const int* __restrict__ cnt, int* __restrict__ offs)
{
    __shared__ int part[1024];
    const int t = threadIdx.x;
    const int CH = (NSEG + 1023) / 1024;  // 40
    const int base = t * CH;
    int s = 0;
    for (int i = 0; i < CH; ++i) {
        const int idx = base + i;
        if (idx < NSEG) s += cnt[idx];
    }
    part[t] = s;
    __syncthreads();
    for (int off = 1; off < 1024; off <<= 1) {
        int v = (t >= off) ? part[t - off] : 0;
        __syncthreads();
        part[t] += v;
        __syncthreads();
    }
    int run = (t == 0) ? 0 : part[t - 1];
    for (int i = 0; i < CH; ++i) {
        const int idx = base + i;
        if (idx < NSEG) { offs[idx] = run; run += cnt[idx]; }
    }
    if (t == 1023) offs[NSEG] = run;  // total = NEDGE
}

// ---------------------------------------------------------------------------
// Kernel 3: scatter packed (src, coeff) into CSR slots. One thread per edge.
// ---------------------------------------------------------------------------
__global__ __launch_bounds__(256) void fill_kernel(
    const int* __restrict__ eidx, const float* __restrict__ coeff,
    const int* __restrict__ offs, int* __restrict__ cursor,
    int2* __restrict__ epair)
{
    const int eg = (int)(blockIdx.x * blockDim.x + threadIdx.x);
    if (eg >= NEDGE) return;
    const int b   = eg / Ec;
    const int src = eidx[(size_t)eg * 2 + 0];
    const int tgt = eidx[(size_t)eg * 2 + 1];
    const int seg = b * Nc + tgt;
    const int slot = offs[seg] + atomicAdd(&cursor[seg], 1);
    epair[slot] = make_int2(src, __float_as_int(coeff[eg]));
}

// ---------------------------------------------------------------------------
// Kernel 4: per-node register accumulation over CSR edge list. One wave/node.
// nhf rows are bf16 (128 uints per 256-elem node row; uint2 per lane).
// Unroll x8 (4 KB row-bytes in flight), acc[4] rotation for FMA ILP.
// ---------------------------------------------------------------------------
__global__ __launch_bounds__(256) void gather_kernel(
    const int* __restrict__ offs, const int2* __restrict__ epair,
    const unsigned* __restrict__ nhf, float* __restrict__ out)
{
    const int lane = threadIdx.x & 63;
    int seg = (int)((blockIdx.x * blockDim.x + threadIdx.x) >> 6);
    if (seg >= NSEG) return;
    seg = __builtin_amdgcn_readfirstlane(seg);
    const int b = seg / Nc;
    const int start = offs[seg], end = offs[seg + 1];
    const unsigned* base = nhf + (size_t)b * Nc * 128 + lane * 2;

    f32x4 acc[4];
#pragma unroll
    for (int j = 0; j < 4; ++j) acc[j] = (f32x4){0.f, 0.f, 0.f, 0.f};

    int i = start;
    for (; i + 8 <= end; i += 8) {
        int2 p[8]; uint2 r[8];
#pragma unroll
        for (int j = 0; j < 8; ++j) p[j] = epair[i + j];
#pragma unroll
        for (int j = 0; j < 8; ++j) r[j] = *(const uint2*)(base + (size_t)p[j].x * 128);
#pragma unroll
        for (int j = 0; j < 8; ++j) {
            const float c = __int_as_float(p[j].y);
            acc[j & 3][0] += c * bflo(r[j].x);
            acc[j & 3][1] += c * bfhi(r[j].x);
            acc[j & 3][2] += c * bflo(r[j].y);
            acc[j & 3][3] += c * bfhi(r[j].y);
        }
    }
    if (i + 4 <= end) {
        int2 p[4]; uint2 r[4];
#pragma unroll
        for (int j = 0; j < 4; ++j) p[j] = epair[i + j];
#pragma unroll
        for (int j = 0; j < 4; ++j) r[j] = *(const uint2*)(base + (size_t)p[j].x * 128);
#pragma unroll
        for (int j = 0; j < 4; ++j) {
            const float c = __int_as_float(p[j].y);
            acc[j][0] += c * bflo(r[j].x);
            acc[j][1] += c * bfhi(r[j].x);
            acc[j][2] += c * bflo(r[j].y);
            acc[j][3] += c * bfhi(r[j].y);
        }
        i += 4;
    }
    for (; i < end; ++i) {
        const int2 p = epair[i];
        const uint2 r = *(const uint2*)(base + (size_t)p.x * 128);
        const float c = __int_as_float(p.y);
        acc[0][0] += c * bflo(r.x);
        acc[0][1] += c * bfhi(r.x);
        acc[0][2] += c * bflo(r.y);
        acc[0][3] += c * bfhi(r.y);
    }
    float4 o;
    o.x = (acc[0][0] + acc[1][0]) + (acc[2][0] + acc[3][0]);
    o.y = (acc[0][1] + acc[1][1]) + (acc[2][1] + acc[3][1]);
    o.z = (acc[0][2] + acc[1][2]) + (acc[2][2] + acc[3][2]);
    o.w = (acc[0][3] + acc[1][3]) + (acc[2][3] + acc[3][3]);
    *(float4*)(out + (size_t)seg * 256 + lane * 4) = o;
}

// ---------------------------------------------------------------------------
// Fallback (ws too small): per-edge atomic scatter over bf16 nhf.
// ---------------------------------------------------------------------------
__global__ __launch_bounds__(256) void edge_atomic_kernel(
    const float* __restrict__ efts, const int* __restrict__ eidx,
    const float* __restrict__ We, const float* __restrict__ be,
    const unsigned* __restrict__ nhf, float* __restrict__ out)
{
    const int lane = threadIdx.x & 63;
    const int eg   = (int)((blockIdx.x * blockDim.x + threadIdx.x) >> 6);
    if (eg >= NEDGE) return;
    const int b = eg / Ec;
    float c = efts[(size_t)eg * 64 + lane] * We[lane];
#pragma unroll
    for (int off = 32; off > 0; off >>= 1) c += __shfl_xor(c, off, 64);
    c += be[0];
    const int src = eidx[(size_t)eg * 2 + 0];
    const int tgt = eidx[(size_t)eg * 2 + 1];
    const uint2 r = *(const uint2*)(nhf + ((size_t)(b * Nc + src)) * 128 + lane * 2);
    float* op = out + ((size_t)(b * Nc + tgt)) * 256 + lane * 4;
    atomicAdd(op + 0, c * bflo(r.x));
    atomicAdd(op + 1, c * bfhi(r.x));
    atomicAdd(op + 2, c * bflo(r.y));
    atomicAdd(op + 3, c * bfhi(r.y));
}

extern "C" void kernel_launch(void* const* d_in, const int* in_sizes, int n_in,
                              void* d_out, int out_size, void* d_ws, size_t ws_size,
                              hipStream_t stream) {
    const float* node = (const float*)d_in[0];  // [B,N,M,H]
    const float* hid  = (const float*)d_in[1];  // [B,N,M,H]
    const float* efts = (const float*)d_in[2];  // [B,E,F]
    const float* Wnh  = (const float*)d_in[3];  // [2H,OUT]
    const float* bnh  = (const float*)d_in[4];  // [OUT]
    const float* We   = (const float*)d_in[5];  // [F,1]
    const float* be   = (const float*)d_in[6];  // [1]
    const int*   eidx = (const int*)d_in[7];    // [B,E,2] int32
    float* out = (float*)d_out;                 // [B,N,M,OUT]

    // Workspace layout (4-byte element offsets):
    //   nhf16  [0,         5,120,000)  bf16 projected features (10.24M ushort)
    //   coeff  [5,120,000, 5,760,000)  per-edge gate (float)
    //   epair  [5,760,000, 7,040,000)  CSR (src, coeff) int2 pairs
    //   cnt    [7,040,000, 7,080,000)
    //   cursor [7,080,000, 7,120,000)
    //   offs   [7,120,000, 7,160,001)
    unsigned* ws   = (unsigned*)d_ws;
    unsigned short* nhf16 = (unsigned short*)ws;
    float* coeff   = (float*)(ws + 5120000);
    int2*  epair   = (int2*)(ws + 5760000);
    int*   cnt     = (int*)(ws + 7040000);
    int*   cursor  = (int*)(ws + 7080000);
    int*   offs    = (int*)(ws + 7120000);
    const size_t ws_needed = (size_t)7160001 * 4;

    if (ws_size >= ws_needed) {
        hipMemsetAsync(cnt, 0, (size_t)80000 * sizeof(int), stream);  // cnt+cursor
        proj_gate_kernel<<<PROJ_BLOCKS + GATE_BLOCKS, 256, 0, stream>>>(
            node, hid, Wnh, bnh, nhf16, efts, eidx, We, be, coeff, cnt);
        scan_kernel<<<1, 1024, 0, stream>>>(cnt, offs);
        fill_kernel<<<NEDGE / 256, 256, 0, stream>>>(eidx, coeff, offs, cursor, epair);
        gather_kernel<<<NSEG / 4, 256, 0, stream>>>(offs, epair, (const unsigned*)ws, out);
    } else {
        // fallback: separate proj (grid-stride form packed into fused kernel needs
        // full grid; just run fused with gate targets pointing at coeff-less path
        // is not possible — use atomic path with a minimal 20.5 MB nhf)
        proj_gate_kernel<<<PROJ_BLOCKS, 256, 0, stream>>>(
            node, hid, Wnh, bnh, nhf16, efts, eidx, We, be,
            (float*)d_out /*unused*/, (int*)d_out /*unused*/);
        hipMemsetAsync(d_out, 0, (size_t)out_size * sizeof(float), stream);
        edge_atomic_kernel<<<NEDGE / 4, 256, 0, stream>>>(efts, eidx, We, be, (const unsigned*)ws, out);
    }
}